// Round 12
// baseline (659.534 us; speedup 1.0000x reference)
//
#include <hip/hip_runtime.h>

typedef unsigned int u32;
typedef unsigned long long u64;

// ---------------- ws layout (u32 units) ----------------
#define WQ1  0      // uint4[32]  : {b|n<<16, Tpack_lo, Tpack_hi, 0}
#define WQ2  128    // [64][12]   : {b0,n0,b1,n1,b2,n2, T0,TL,TR, 0,0,0}
#define WQ3  896    // [128][16]  : {b00,n00,b01,n01,b10,n10,b11,n11,b20,n20,b21,n21, T0,TL,TR,0}
#define WQ4  2944   // [128][6][8]: per r {b0,b1,b2,b3, n0,n1,n2,n3}
#define WNA4 9088   // int[128]
#define WSC4 9216   // float[128]   (total 9344 u32 = 37376 B)

__device__ __forceinline__ int scanT(int na, float bb, float mm, float sc, float be, int lim) {
  for (int nm = 0; nm <= lim; ++nm) {
    float tt = (((float)(na - 2 * nm) + bb) - mm) * sc + be;
    if (tt < 0.0f) return nm;
  }
  return 1 << 20;  // never negative
}

__global__ void setup_pack(
    const float* __restrict__ w1, const float* __restrict__ w2,
    const float* __restrict__ w3, const float* __restrict__ w4,
    const float* __restrict__ b1, const float* __restrict__ g1, const float* __restrict__ be1,
    const float* __restrict__ m1, const float* __restrict__ v1,
    const float* __restrict__ b2, const float* __restrict__ g2, const float* __restrict__ be2,
    const float* __restrict__ m2, const float* __restrict__ v2,
    const float* __restrict__ b3, const float* __restrict__ g3, const float* __restrict__ be3,
    const float* __restrict__ m3, const float* __restrict__ v3,
    const float* __restrict__ g4, const float* __restrict__ v4,
    u32* __restrict__ ws) {
  const int t = threadIdx.x;
  if (t < 32) {                       // ---- L1 ----
    const int c = t;
    u32 wb = 0, wn = 0;
    for (int k = 0; k < 9; ++k) {
      float f = w1[c * 9 + k];
      if (f < 0.0f) wb |= 1u << k;
      if (f != 0.0f) wn |= 1u << k;
    }
    float sc = g1[c] / sqrtf(v1[c] + 1e-5f);
    u64 pack = 0;
    for (int v = 0; v <= 9; ++v) {
      u32 T = 15;
      for (int p = 0; p <= 9; ++p) {
        float tt = (((float)(v - 2 * p) + b1[c]) - m1[c]) * sc + be1[c];
        if (tt < 0.0f) { T = (u32)p; break; }
      }
      pack |= (u64)T << (4 * v);
    }
    u32* W = ws + WQ1 + c * 4;
    W[0] = wb | (wn << 16);
    W[1] = (u32)pack;
    W[2] = (u32)(pack >> 32);
    W[3] = 0;
  } else if (t < 96) {                // ---- L2 ----
    const int c = t - 32;
    u32 wb[3], wn[3];
    for (int k = 0; k < 3; ++k) {
      u32 b = 0, nn = 0;
      for (int ci = 0; ci < 32; ++ci) {
        float f = w2[(c * 32 + ci) * 3 + k];
        if (f < 0.0f) b |= 1u << ci;
        if (f != 0.0f) nn |= 1u << ci;
      }
      wb[k] = b; wn[k] = nn;
    }
    float sc = g2[c] / sqrtf(v2[c] + 1e-5f);
    int naI = __popc(wn[0]) + __popc(wn[1]) + __popc(wn[2]);
    int naL = __popc(wn[1]) + __popc(wn[2]);
    int naR = __popc(wn[0]) + __popc(wn[1]);
    int T0 = scanT(naI, b2[c], m2[c], sc, be2[c], 97);
    int TL = scanT(naL, b2[c], m2[c], sc, be2[c], 97) + __popc(wb[0] & wn[0]);
    int TR = scanT(naR, b2[c], m2[c], sc, be2[c], 97) + __popc(wb[2] & wn[2]);
    u32* W = ws + WQ2 + c * 12;
    W[0] = wb[0]; W[1] = wn[0]; W[2] = wb[1]; W[3] = wn[1]; W[4] = wb[2]; W[5] = wn[2];
    W[6] = (u32)T0; W[7] = (u32)TL; W[8] = (u32)TR; W[9] = 0; W[10] = 0; W[11] = 0;
  } else if (t < 224) {               // ---- L3 ----
    const int c = t - 96;
    u32 wb[3][2], wn[3][2];
    for (int k = 0; k < 3; ++k)
      for (int g = 0; g < 2; ++g) {
        u32 b = 0, nn = 0;
        for (int xx = 0; xx < 32; ++xx) {
          int ci = g * 32 + xx;
          float f = w3[(c * 64 + ci) * 3 + k];
          if (f < 0.0f) b |= 1u << xx;
          if (f != 0.0f) nn |= 1u << xx;
        }
        wb[k][g] = b; wn[k][g] = nn;
      }
    float sc = g3[c] / sqrtf(v3[c] + 1e-5f);
    int n0 = __popc(wn[0][0]) + __popc(wn[0][1]);
    int n1 = __popc(wn[1][0]) + __popc(wn[1][1]);
    int n2 = __popc(wn[2][0]) + __popc(wn[2][1]);
    int T0 = scanT(n0 + n1 + n2, b3[c], m3[c], sc, be3[c], 193);
    int TL = scanT(n1 + n2, b3[c], m3[c], sc, be3[c], 193)
             + __popc(wb[0][0] & wn[0][0]) + __popc(wb[0][1] & wn[0][1]);
    int TR = scanT(n0 + n1, b3[c], m3[c], sc, be3[c], 193)
             + __popc(wb[2][0] & wn[2][0]) + __popc(wb[2][1] & wn[2][1]);
    u32* W = ws + WQ3 + c * 16;
    for (int k = 0; k < 3; ++k)
      for (int g = 0; g < 2; ++g) { W[(k * 2 + g) * 2] = wb[k][g]; W[(k * 2 + g) * 2 + 1] = wn[k][g]; }
    W[12] = (u32)T0; W[13] = (u32)TL; W[14] = (u32)TR; W[15] = 0;
  } else if (t < 352) {               // ---- L4 ----
    const int c = t - 224;
    int na4 = 0;
    for (int r = 0; r < 6; ++r)
      for (int g = 0; g < 4; ++g) {
        u32 b = 0, nn = 0;
        for (int xx = 0; xx < 32; ++xx) {
          int ci = g * 32 + xx;
          float f = w4[(c * 128 + ci) * 6 + r];
          if (f < 0.0f) b |= 1u << xx;
          if (f != 0.0f) nn |= 1u << xx;
        }
        ws[WQ4 + c * 48 + r * 8 + g] = b;
        ws[WQ4 + c * 48 + r * 8 + 4 + g] = nn;
        na4 += __popc(nn);
      }
    ((int*)(ws + WNA4))[c] = na4;
    ((float*)(ws + WSC4))[c] = g4[c] / sqrtf(v4[c] + 1e-5f);
  }
}

// build padded 9-bit windows from ballot planes (k1,k2,sh in scope)
#define MKWIN(nb0, nz0, nb1, nz1, XB, XN)                                          \
  {                                                                                \
    u32 B0 = (u32)(nb0) << 4, B1 = (u32)((nb0) >> 28),                             \
        B2 = (u32)((nb0) >> 60) | ((u32)(nb1) << 4);                               \
    u32 B3 = (u32)((nb1) >> 28), B4 = (u32)((nb1) >> 60);                          \
    u32 N0 = (u32)(nz0) << 4, N1 = (u32)((nz0) >> 28),                             \
        N2 = (u32)((nz0) >> 60) | ((u32)(nz1) << 4);                               \
    u32 N3 = (u32)((nz1) >> 28), N4 = (u32)((nz1) >> 60);                          \
    u32 blo = k2 ? (k1 ? B3 : B2) : (k1 ? B1 : B0);                                \
    u32 bhi = k2 ? (k1 ? B4 : B3) : (k1 ? B2 : B1);                                \
    u32 nlo = k2 ? (k1 ? N3 : N2) : (k1 ? N1 : N0);                                \
    u32 nhi = k2 ? (k1 ? N4 : N3) : (k1 ? N2 : N1);                                \
    XB = (u32)(((((u64)bhi << 32) | blo) >> sh)) & 0x1FF;                          \
    XN = (u32)(((((u64)nhi << 32) | nlo) >> sh)) & 0x1FF;                          \
  }

#define LGKM0() asm volatile("s_waitcnt lgkmcnt(0)" ::: "memory")

// ---------------- fused network: one WAVE per sample, no block barriers ----------------
__global__ __launch_bounds__(384) void bnn_fused(
    const float* __restrict__ x,
    const float* __restrict__ b4, const float* __restrict__ m4, const float* __restrict__ be4,
    const float* __restrict__ wfc, const float* __restrict__ bfc,
    const u32* __restrict__ ws, float* __restrict__ out, int N) {
  __shared__ u32 s1b[6][6 * 34];
  __shared__ u32 s2b[6][6 * 34 * 2];
  __shared__ __align__(16) u32 s3b[6][6 * 16 * 4];

  const int t = threadIdx.x;
  const int lane = t & 63;
  const int wv = t >> 6;                 // wave = sample slot
  const int smp = blockIdx.x * 6 + wv;
  if (smp >= N) return;                  // wave-uniform; no barriers anywhere

  u32* S1 = s1b[wv];
  u32* S2 = s2b[wv];
  u32* S3 = s3b[wv];

  // ---- Phase A: L1 conv(1x9,s2,p4)+pool, 6 rows looped in-wave ----
  {
    const float* xs = x + smp * 768;
    int sp = lane * 2, kk = sp >> 5, sh = sp & 31;
    bool k1 = (kk & 1) != 0, k2 = (kk & 2) != 0;
    const uint4* q1 = (const uint4*)(ws + WQ1);
#pragma unroll
    for (int r = 0; r < 6; ++r) {
      float x0 = xs[r * 128 + lane], x1 = xs[r * 128 + 64 + lane];
      u64 nb0 = __ballot(x0 < 0.0f), nz0 = __ballot(x0 != 0.0f);
      u64 nb1 = __ballot(x1 < 0.0f), nz1 = __ballot(x1 != 0.0f);
      u32 xb, xn;
      MKWIN(nb0, nz0, nb1, nz1, xb, xn);
      u32 word = 0;
#pragma unroll 8
      for (int c = 0; c < 32; ++c) {
        uint4 q = q1[c];
        u32 wb = q.x & 0x1FF, wn = q.x >> 16;
        u64 P = ((u64)q.z << 32) | q.y;
        u32 m = xn & wn;
        int p1 = __popc((xb ^ wb) & m) + 1;
        int T = (int)((u32)(P >> ((u32)__popc(m) << 2)) & 15u);
        word |= ((u32)(T - p1) >> 31) << c;
      }
      u32 pooled = word & __shfl_xor(word, 1, 64);
      if (!(lane & 1)) S1[r * 34 + 1 + (lane >> 1)] = pooled;
      if (lane == 1) S1[r * 34] = 0;
      if (lane == 3) S1[r * 34 + 33] = 0;
    }
  }
  LGKM0();

  // ---- Phase B: L2 conv(1x3,p1) sign bits; lanes = 2 rows x 32 positions ----
  {
    if (lane < 24) {                     // zero s2 pad columns
      int rr = lane >> 2, side = (lane >> 1) & 1, g = lane & 1;
      S2[(rr * 34 + side * 33) * 2 + g] = 0;
    }
    const int w = lane & 31;
    const bool cL = (w == 0), cR = (w == 31);
#pragma unroll
    for (int it = 0; it < 3; ++it) {
      int r = 2 * it + (lane >> 5);
      u32 X0 = S1[r * 34 + w], X1 = S1[r * 34 + w + 1], X2 = S1[r * 34 + w + 2];
#pragma unroll
      for (int hs = 0; hs < 2; ++hs) {
        const u32* q2 = ws + WQ2 + hs * 32 * 12;
        u32 word = 0;
#pragma unroll 4
        for (int i = 0; i < 32; ++i) {
          const u32* W = q2 + i * 12;
          int T = cL ? (int)W[7] : (cR ? (int)W[8] : (int)W[6]);
          int nm1 = __popc((X0 ^ W[0]) & W[1]) + __popc((X1 ^ W[2]) & W[3])
                  + __popc((X2 ^ W[4]) & W[5]) + 1;
          word |= ((u32)(T - nm1) >> 31) << i;
        }
        S2[(r * 34 + w + 1) * 2 + hs] = word;
      }
    }
  }
  LGKM0();

  // ---- Phase C: L3 conv(1x3,p1)+pool sign bits ----
  {
    const int w = lane & 31;
    const bool cL = (w == 0), cR = (w == 31);
#pragma unroll
    for (int it = 0; it < 3; ++it) {
      int r = 2 * it + (lane >> 5);
      const u32* S = S2 + (r * 34 + w) * 2;
      u32 X0 = S[0], X1 = S[1], X2 = S[2], X3 = S[3], X4 = S[4], X5 = S[5];
#pragma unroll
      for (int hs = 0; hs < 2; ++hs) {
        const u32* q3 = ws + WQ3 + hs * 64 * 16;
        u32 w0 = 0, w1 = 0;
#pragma unroll 2
        for (int i = 0; i < 32; ++i) {
          {
            const u32* W = q3 + i * 16;
            int T = cL ? (int)W[13] : (cR ? (int)W[14] : (int)W[12]);
            int nm1 = __popc((X0 ^ W[0]) & W[1]) + __popc((X1 ^ W[2]) & W[3])
                    + __popc((X2 ^ W[4]) & W[5]) + __popc((X3 ^ W[6]) & W[7])
                    + __popc((X4 ^ W[8]) & W[9]) + __popc((X5 ^ W[10]) & W[11]) + 1;
            w0 |= ((u32)(T - nm1) >> 31) << i;
          }
          {
            const u32* W = q3 + (i + 32) * 16;
            int T = cL ? (int)W[13] : (cR ? (int)W[14] : (int)W[12]);
            int nm1 = __popc((X0 ^ W[0]) & W[1]) + __popc((X1 ^ W[2]) & W[3])
                    + __popc((X2 ^ W[4]) & W[5]) + __popc((X3 ^ W[6]) & W[7])
                    + __popc((X4 ^ W[8]) & W[9]) + __popc((X5 ^ W[10]) & W[11]) + 1;
            w1 |= ((u32)(T - nm1) >> 31) << i;
          }
        }
        u32 p0 = w0 & __shfl_xor(w0, 1, 64);
        u32 p1 = w1 & __shfl_xor(w1, 1, 64);
        if (!(lane & 1)) {
          int j = w >> 1;
          S3[(r * 16 + j) * 4 + hs * 2] = p0;
          S3[(r * 16 + j) * 4 + hs * 2 + 1] = p1;
        }
      }
    }
  }
  LGKM0();

  // ---- Phase D+E fused: L4 conv + BN + htanh in regs, then FC in regs ----
  float hv[4][8];
  {
#pragma unroll
    for (int it = 0; it < 4; ++it) {
      const int c = it * 32 + (lane >> 1), q8 = (lane & 1) * 8;
      int nm[8];
#pragma unroll
      for (int j = 0; j < 8; ++j) nm[j] = 0;
      const uint4* Wb = (const uint4*)(ws + WQ4 + c * 48);
#pragma unroll
      for (int r = 0; r < 6; ++r) {
        uint4 bv = Wb[r * 2], nv = Wb[r * 2 + 1];
#pragma unroll
        for (int j = 0; j < 8; ++j) {
          uint4 xv = *((const uint4*)S3 + r * 16 + q8 + j);
          nm[j] += __popc((xv.x ^ bv.x) & nv.x) + __popc((xv.y ^ bv.y) & nv.y)
                 + __popc((xv.z ^ bv.z) & nv.z) + __popc((xv.w ^ bv.w) & nv.w);
        }
      }
      const int nav = ((const int*)(ws + WNA4))[c];
      const float base = b4[c] - m4[c];
      const float scv = ((const float*)(ws + WSC4))[c];
      const float bev = be4[c];
#pragma unroll
      for (int j = 0; j < 8; ++j) {
        float tt = ((float)(nav - 2 * nm[j]) + base) * scv + bev;
        hv[it][j] = fminf(1.0f, fmaxf(-1.0f, tt));
      }
    }
  }
  // FC (2048 -> 10): lane owns h4 flat [it*512 + lane*8 .. +8)
  {
    float acc[10];
#pragma unroll
    for (int o = 0; o < 10; ++o) {
      float a = 0.0f;
#pragma unroll
      for (int it = 0; it < 4; ++it) {
        const float* wr = wfc + o * 2048 + it * 512 + lane * 8;
#pragma unroll
        for (int u = 0; u < 8; ++u) a += hv[it][u] * wr[u];
      }
      acc[o] = a;
    }
#pragma unroll
    for (int o = 0; o < 10; ++o) {
      float v = acc[o];
#pragma unroll
      for (int sft = 32; sft >= 1; sft >>= 1) v += __shfl_down(v, sft, 64);
      acc[o] = v;
    }
    if (lane == 0) {
#pragma unroll
      for (int o = 0; o < 10; ++o) out[smp * 10 + o] = acc[o] + bfc[o];
    }
  }
}

extern "C" void kernel_launch(void* const* d_in, const int* in_sizes, int n_in,
                              void* d_out, int out_size, void* d_ws, size_t ws_size,
                              hipStream_t stream) {
  const float* x   = (const float*)d_in[0];
  const float* w1  = (const float*)d_in[1];
  const float* w2  = (const float*)d_in[2];
  const float* w3  = (const float*)d_in[3];
  const float* w4  = (const float*)d_in[4];
  const float* b1  = (const float*)d_in[5];
  const float* g1  = (const float*)d_in[6];
  const float* be1 = (const float*)d_in[7];
  const float* m1  = (const float*)d_in[8];
  const float* v1  = (const float*)d_in[9];
  const float* b2  = (const float*)d_in[10];
  const float* g2  = (const float*)d_in[11];
  const float* be2 = (const float*)d_in[12];
  const float* m2  = (const float*)d_in[13];
  const float* v2  = (const float*)d_in[14];
  const float* b3  = (const float*)d_in[15];
  const float* g3  = (const float*)d_in[16];
  const float* be3 = (const float*)d_in[17];
  const float* m3  = (const float*)d_in[18];
  const float* v3  = (const float*)d_in[19];
  const float* b4  = (const float*)d_in[20];
  const float* g4  = (const float*)d_in[21];
  const float* be4 = (const float*)d_in[22];
  const float* m4  = (const float*)d_in[23];
  const float* v4  = (const float*)d_in[24];
  const float* wfc = (const float*)d_in[25];
  const float* bfc = (const float*)d_in[26];
  u32* ws = (u32*)d_ws;
  float* out = (float*)d_out;

  const int N = in_sizes[0] / 768;   // 8192 samples
  const int NB = (N + 5) / 6;        // one wave per sample, 6 waves per block

  setup_pack<<<1, 384, 0, stream>>>(w1, w2, w3, w4,
                                    b1, g1, be1, m1, v1,
                                    b2, g2, be2, m2, v2,
                                    b3, g3, be3, m3, v3,
                                    g4, v4, ws);
  bnn_fused<<<NB, 384, 0, stream>>>(x, b4, m4, be4, wfc, bfc, ws, out, N);
}